// Round 1
// baseline (3440.276 us; speedup 1.0000x reference)
//
#include <hip/hip_runtime.h>
#include <hip/hip_bf16.h>
#include <math.h>

// LSTM greedy decoder, fp32 throughout (argmax decisions must match JAX exactly;
// bf16 inputs would flip ~1% of argmax decisions -> cascade failure).
//
// Layouts: all activations k-major: xT/hT/cT = [512 k][128 b] so lanes (b-fastest)
// are coalesced everywhere. Gates partial buffer pT[ks][n][b] with gate-interleaved
// n = 4*j + g so the cell kernel reads i,f,g,o of one j contiguously.

#define B 128
#define E 512
#define H 512
#define V 32000
#define TSEQ 20
#define NG 2048            // 4*H
#define NBLK_LOGITS 500    // 32000 / 64

__device__ __forceinline__ float sigmoidf_(float x) { return 1.0f / (1.0f + expf(-x)); }

// ---- init: features -> xT (transposed), zero hT/cT -------------------------
__global__ __launch_bounds__(256) void init_kernel(const float* __restrict__ features,
                                                   float* __restrict__ xT,
                                                   float* __restrict__ hT,
                                                   float* __restrict__ cT) {
    int g = blockIdx.x * 256 + threadIdx.x;   // 0..65535
    int j = g >> 7, b = g & 127;
    xT[g] = features[b * E + j];
    hT[g] = 0.0f;
    cT[g] = 0.0f;
}

// ---- gates GEMM: pT[ks][n][b] += [x|h] @ W^T (k-split over blockIdx.y) ------
// block tile: 128 b x 32 n, K-range 256 per ks. thread tile 4b x 4n.
__global__ __launch_bounds__(256) void gates_kernel(const float* __restrict__ xT,
                                                    const float* __restrict__ hT,
                                                    const float* __restrict__ W_ih,
                                                    const float* __restrict__ W_hh,
                                                    float* __restrict__ pT) {
    const int ntile = blockIdx.x;   // 0..63
    const int ks = blockIdx.y;      // 0..3
    const int tid = threadIdx.x;
    const int nt = tid & 7;         // n0 = nt*4
    const int bt = tid >> 3;        // b0 = bt*4
    __shared__ float xs[64][132];   // activation chunk [k][b], pad->16B aligned rows
    __shared__ float ws[64][36];    // weight chunk transposed [k][n]
    float acc[4][4];
#pragma unroll
    for (int i = 0; i < 4; ++i)
#pragma unroll
        for (int j = 0; j < 4; ++j) acc[i][j] = 0.0f;

    for (int ch = 0; ch < 4; ++ch) {
        const int kb = ks * 256 + ch * 64;    // global k (0..1023), 512 boundary aligned
        const bool isX = (kb < E);
        const float* __restrict__ src = isX ? (xT + (size_t)kb * B) : (hT + (size_t)(kb - E) * B);
        // stage activations: 64x128 floats, coalesced float4
#pragma unroll
        for (int i = 0; i < 8; ++i) {
            int kk = tid >> 2;
            int bb = (tid & 3) * 32 + i * 4;
            float4 v = *reinterpret_cast<const float4*>(src + kk * B + bb);
            *reinterpret_cast<float4*>(&xs[kk][bb]) = v;
        }
        // stage weights transposed: 32 rows (gate-interleaved n) x 64 k
#pragma unroll
        for (int i = 0; i < 2; ++i) {
            int flat = tid * 8 + i * 4;
            int r = flat >> 6;        // 0..31
            int kk = flat & 63;
            int nglob = ntile * 32 + r;
            int jrow = nglob >> 2, gg = nglob & 3;
            const float* __restrict__ Wp = isX ? (W_ih + (size_t)(gg * H + jrow) * E + kb)
                                               : (W_hh + (size_t)(gg * H + jrow) * H + (kb - E));
            float4 w = *reinterpret_cast<const float4*>(Wp + kk);
            ws[kk + 0][r] = w.x;
            ws[kk + 1][r] = w.y;
            ws[kk + 2][r] = w.z;
            ws[kk + 3][r] = w.w;
        }
        __syncthreads();
#pragma unroll
        for (int k = 0; k < 64; ++k) {
            const float4 xv = *reinterpret_cast<const float4*>(&xs[k][bt * 4]);
            const float4 wv = *reinterpret_cast<const float4*>(&ws[k][nt * 4]);
            float xr[4] = {xv.x, xv.y, xv.z, xv.w};
            float wr[4] = {wv.x, wv.y, wv.z, wv.w};
#pragma unroll
            for (int i = 0; i < 4; ++i)
#pragma unroll
                for (int j = 0; j < 4; ++j) acc[i][j] += xr[i] * wr[j];
        }
        __syncthreads();
    }
#pragma unroll
    for (int nj = 0; nj < 4; ++nj) {
        float4 col = make_float4(acc[0][nj], acc[1][nj], acc[2][nj], acc[3][nj]);
        size_t n = (size_t)ks * NG + ntile * 32 + nt * 4 + nj;
        *reinterpret_cast<float4*>(&pT[n * B + bt * 4]) = col;
    }
}

// ---- LSTM cell: sum k-split partials + bias, activations, update cT/hT -----
__global__ __launch_bounds__(256) void cell_kernel(const float* __restrict__ pT,
                                                   const float* __restrict__ b_ih,
                                                   const float* __restrict__ b_hh,
                                                   float* __restrict__ cT,
                                                   float* __restrict__ hT) {
    int tid = threadIdx.x;
    int b = tid & 127;
    int j = blockIdx.x * 2 + (tid >> 7);
    float gs[4];
#pragma unroll
    for (int g = 0; g < 4; ++g) {
        float s = b_ih[g * H + j] + b_hh[g * H + j];
#pragma unroll
        for (int ks = 0; ks < 4; ++ks) s += pT[((size_t)ks * NG + 4 * j + g) * B + b];
        gs[g] = s;
    }
    float ig = sigmoidf_(gs[0]);
    float fg = sigmoidf_(gs[1]);
    float gg = tanhf(gs[2]);
    float og = sigmoidf_(gs[3]);
    float c = fg * cT[j * B + b] + ig * gg;
    cT[j * B + b] = c;
    hT[j * B + b] = og * tanhf(c);
}

// ---- logits GEMM + per-tile argmax: tile 128 b x 64 n, K=512 ---------------
// thread tile 4b x 8n (n = nt*4 + c + 32*q). Epilogue: bias + argmax over the
// 64-n tile via 8-lane shuffle reduce; writes (max,idx) partials per (tile,b).
__global__ __launch_bounds__(256) void logits_kernel(const float* __restrict__ hT,
                                                     const float* __restrict__ W_fc,
                                                     const float* __restrict__ b_fc,
                                                     float* __restrict__ pval,
                                                     int* __restrict__ pidx) {
    const int nblk = blockIdx.x;    // 0..499
    const int tid = threadIdx.x;
    const int nt = tid & 7;
    const int bt = tid >> 3;
    __shared__ float hs[64][132];
    __shared__ float wsl[64][68];
    float acc[4][8];
#pragma unroll
    for (int i = 0; i < 4; ++i)
#pragma unroll
        for (int j = 0; j < 8; ++j) acc[i][j] = 0.0f;

    for (int ch = 0; ch < 8; ++ch) {
        const int kb = ch * 64;
#pragma unroll
        for (int i = 0; i < 8; ++i) {
            int kk = tid >> 2;
            int bb = (tid & 3) * 32 + i * 4;
            float4 v = *reinterpret_cast<const float4*>(hT + (size_t)(kb + kk) * B + bb);
            *reinterpret_cast<float4*>(&hs[kk][bb]) = v;
        }
#pragma unroll
        for (int i = 0; i < 4; ++i) {
            int r = tid >> 2;                 // 0..63 (row within n-tile)
            int kk = (tid & 3) * 16 + i * 4;
            float4 w = *reinterpret_cast<const float4*>(W_fc + (size_t)(nblk * 64 + r) * E + kb + kk);
            wsl[kk + 0][r] = w.x;
            wsl[kk + 1][r] = w.y;
            wsl[kk + 2][r] = w.z;
            wsl[kk + 3][r] = w.w;
        }
        __syncthreads();
#pragma unroll
        for (int k = 0; k < 64; ++k) {
            const float4 xv = *reinterpret_cast<const float4*>(&hs[k][bt * 4]);
            const float4 w0 = *reinterpret_cast<const float4*>(&wsl[k][nt * 4]);
            const float4 w1 = *reinterpret_cast<const float4*>(&wsl[k][nt * 4 + 32]);
            float xr[4] = {xv.x, xv.y, xv.z, xv.w};
            float wr[8] = {w0.x, w0.y, w0.z, w0.w, w1.x, w1.y, w1.z, w1.w};
#pragma unroll
            for (int i = 0; i < 4; ++i)
#pragma unroll
                for (int j = 0; j < 8; ++j) acc[i][j] += xr[i] * wr[j];
        }
        __syncthreads();
    }

    const int n_base = nblk * 64;
    float bf[8];
#pragma unroll
    for (int q = 0; q < 2; ++q)
#pragma unroll
        for (int c = 0; c < 4; ++c) bf[q * 4 + c] = b_fc[n_base + nt * 4 + c + 32 * q];

#pragma unroll
    for (int bi = 0; bi < 4; ++bi) {
        float bestv = -INFINITY;
        int bestn = 0x7fffffff;
#pragma unroll
        for (int q = 0; q < 2; ++q)
#pragma unroll
            for (int c = 0; c < 4; ++c) {
                float v = acc[bi][q * 4 + c] + bf[q * 4 + c];
                int n = n_base + nt * 4 + c + 32 * q;
                if (v > bestv || (v == bestv && n < bestn)) { bestv = v; bestn = n; }
            }
#pragma unroll
        for (int off = 1; off < 8; off <<= 1) {   // reduce across the 8 nt lanes
            float ov = __shfl_xor(bestv, off);
            int on = __shfl_xor(bestn, off);
            if (ov > bestv || (ov == bestv && on < bestn)) { bestv = ov; bestn = on; }
        }
        if (nt == 0) {
            int b = bt * 4 + bi;
            pval[(size_t)nblk * B + b] = bestv;
            pidx[(size_t)nblk * B + b] = bestn;
        }
    }
}

// ---- final argmax over 500 partials + write outputs + embedding gather -----
// Each of 64 blocks redundantly reduces (cheap, L2-resident) so all blocks know
// idx[b]; block 0 writes ids/vals; every block gathers its 8-j slice into xT.
__global__ __launch_bounds__(256) void argmax_gather_kernel(const float* __restrict__ pval,
                                                            const int* __restrict__ pidx,
                                                            const float* __restrict__ emb,
                                                            float* __restrict__ xT,
                                                            float* __restrict__ out,
                                                            int t) {
    __shared__ float sv[256];
    __shared__ int si[256];
    __shared__ int widx[128];
    int tid = threadIdx.x;
    int b = tid & 127;
    int half = tid >> 7;
    float bestv = -INFINITY;
    int besti = 0x7fffffff;
    for (int p = half; p < NBLK_LOGITS; p += 2) {
        float v = pval[(size_t)p * B + b];
        int ii = pidx[(size_t)p * B + b];
        if (v > bestv || (v == bestv && ii < besti)) { bestv = v; besti = ii; }
    }
    sv[tid] = bestv;
    si[tid] = besti;
    __syncthreads();
    if (half == 0) {
        float v1 = sv[tid + 128];
        int i1 = si[tid + 128];
        if (v1 > bestv || (v1 == bestv && i1 < besti)) { bestv = v1; besti = i1; }
        widx[b] = besti;
        if (blockIdx.x == 0) {
            out[b * TSEQ + t] = (float)besti;            // ids, [B][T]
            out[B * TSEQ + b * TSEQ + t] = bestv;        // vals, [B][T]
        }
    }
    __syncthreads();
#pragma unroll
    for (int q = 0; q < 4; ++q) {
        int j = blockIdx.x * 8 + q * 2 + half;           // 64 blocks x 8 j = 512
        xT[(size_t)j * B + b] = emb[(size_t)widx[b] * E + j];
    }
}

extern "C" void kernel_launch(void* const* d_in, const int* in_sizes, int n_in,
                              void* d_out, int out_size, void* d_ws, size_t ws_size,
                              hipStream_t stream) {
    const float* features = (const float*)d_in[0];
    // d_in[1] = lengths: unused by the reference computation (scan is fixed length)
    const float* emb  = (const float*)d_in[2];
    const float* W_ih = (const float*)d_in[3];
    const float* W_hh = (const float*)d_in[4];
    const float* b_ih = (const float*)d_in[5];
    const float* b_hh = (const float*)d_in[6];
    const float* W_fc = (const float*)d_in[7];
    const float* b_fc = (const float*)d_in[8];
    float* out = (float*)d_out;
    float* ws = (float*)d_ws;

    // workspace layout (floats): total ~5.5 MB
    float* xT = ws;                      // 512*128
    float* hT = xT + 65536;
    float* cT = hT + 65536;
    float* pT = cT + 65536;              // 4*2048*128 = 1048576
    float* pval = pT + 1048576;          // 500*128
    int* pidx = (int*)(pval + (size_t)NBLK_LOGITS * B);

    init_kernel<<<256, 256, 0, stream>>>(features, xT, hT, cT);
    for (int t = 0; t < TSEQ; ++t) {
        gates_kernel<<<dim3(64, 4), 256, 0, stream>>>(xT, hT, W_ih, W_hh, pT);
        cell_kernel<<<256, 256, 0, stream>>>(pT, b_ih, b_hh, cT, hT);
        logits_kernel<<<NBLK_LOGITS, 256, 0, stream>>>(hT, W_fc, b_fc, pval, pidx);
        argmax_gather_kernel<<<64, 256, 0, stream>>>(pval, pidx, emb, xT, out, t);
    }
}

// Round 3
// 1337.568 us; speedup vs baseline: 2.5720x; 2.5720x over previous
//
#include <hip/hip_runtime.h>
#include <hip/hip_bf16.h>
#include <math.h>

// LSTM greedy decoder.
// - gates GEMM: fp32 VALU (accuracy: h errors propagate through the recurrence
//   and cannot be fixed post-hoc), 8x8 thread tiles, K-split 16, LDS-swizzled W,
//   broadcast x reads.
// - logits GEMM: MFMA 16x16x32 bf16 with 2-term split (hi*hi + hi*lo + lo*hi).
//   Argmax safety: per-16n-tile top-2 sortable keys -> global top-2 -> EXACT fp32
//   recompute of both candidates decides the winner (and provides the output val).
// - Needs ~88MB workspace for W_fc hi/lo bf16; falls back to the all-fp32 R1 path
//   if ws_size is too small (deterministic branch; graph-capture safe).

#define B 128
#define E 512
#define H 512
#define V 32000
#define TSEQ 20
#define NG 2048            // 4*H
#define KSPLIT 16          // gates K-split (64 k each over 1024)
#define NTILE_L 128        // logits n per block
#define NBLK_L 250         // 32000/128
#define WTILES 2000        // 250 blocks * 8 waves (16 n each)
#define WTPAD 2048

typedef __attribute__((ext_vector_type(8))) short short8v;
typedef __attribute__((ext_vector_type(4))) float f32x4;
typedef unsigned long long ull;

__device__ __forceinline__ float sigmoidf_(float x) { return 1.0f / (1.0f + expf(-x)); }

__device__ __forceinline__ short f2bf_s(float x) {
    __hip_bfloat16 h = __float2bfloat16(x);
    return *reinterpret_cast<short*>(&h);
}
__device__ __forceinline__ float bfs2f(short s) {
    __hip_bfloat16 h = *reinterpret_cast<__hip_bfloat16*>(&s);
    return __bfloat162float(h);
}
__device__ __forceinline__ ull shflx_u64(ull x, int m) {
    int lo = __shfl_xor((int)(unsigned int)x, m);
    int hi = __shfl_xor((int)(unsigned int)(x >> 32), m);
    return ((ull)(unsigned int)hi << 32) | (unsigned int)lo;
}
// keep (k1,k2) = top-2 keys; merge with another sorted pair (o1,o2); sets disjoint
__device__ __forceinline__ void merge2(ull& k1, ull& k2, ull o1, ull o2) {
    ull a = k1 > o1 ? k1 : o1;
    ull b = k1 > o1 ? o1 : k1;
    ull c = k2 > o2 ? k2 : o2;
    k1 = a;
    k2 = b > c ? b : c;
}
// sortable key: high 32 = monotonic float bits, low 32 = ~n (max key => max v, then min n)
__device__ __forceinline__ ull makekey(float v, unsigned int n) {
    unsigned int u = __float_as_uint(v);
    u ^= (unsigned int)(((int)u >> 31)) | 0x80000000u;
    return ((ull)u << 32) | (0xFFFFFFFFu - n);
}
__device__ __forceinline__ int keyidx(ull k) {
    return (int)(0xFFFFFFFFu - (unsigned int)(k & 0xFFFFFFFFu));
}

// ---- init: features -> xT (transposed), zero hT/cT -------------------------
__global__ __launch_bounds__(256) void init_kernel(const float* __restrict__ features,
                                                   float* __restrict__ xT,
                                                   float* __restrict__ hT,
                                                   float* __restrict__ cT) {
    int g = blockIdx.x * 256 + threadIdx.x;   // 0..65535
    int j = g >> 7, b = g & 127;
    xT[g] = features[b * E + j];
    hT[g] = 0.0f;
    cT[g] = 0.0f;
}

// ---- W_fc fp32 -> bf16 hi/lo split (runs every launch; ws is re-poisoned) ---
__global__ __launch_bounds__(256) void wsplit_kernel(const float* __restrict__ W,
                                                     short* __restrict__ Wh,
                                                     short* __restrict__ Wl) {
    size_t i = ((size_t)blockIdx.x * 256 + threadIdx.x) * 8;
    float4 a = *reinterpret_cast<const float4*>(W + i);
    float4 b = *reinterpret_cast<const float4*>(W + i + 4);
    float xv[8] = {a.x, a.y, a.z, a.w, b.x, b.y, b.z, b.w};
    union { short8v v; short s[8]; } uh, ul;
#pragma unroll
    for (int j = 0; j < 8; ++j) {
        short hs = f2bf_s(xv[j]);
        uh.s[j] = hs;
        ul.s[j] = f2bf_s(xv[j] - bfs2f(hs));
    }
    *reinterpret_cast<short8v*>(Wh + i) = uh.v;
    *reinterpret_cast<short8v*>(Wl + i) = ul.v;
}

// ---- gates GEMM (fp32): pT[ks][n][b], 8x8 thread tile, K-split 16 -----------
// LDS: xs[64][128] ([k][b], compute reads are quarter-wave broadcasts -> free),
//      ws[128][64] ([n][k], 16B slots swizzled by n>>3 -> conflict-free b128).
__global__ __launch_bounds__(256) void gates_kernel(const float* __restrict__ xT,
                                                    const float* __restrict__ hT,
                                                    const float* __restrict__ W_ih,
                                                    const float* __restrict__ W_hh,
                                                    float* __restrict__ pT) {
    const int ntile = blockIdx.x;   // 0..15 (128 n each)
    const int ks = blockIdx.y;      // 0..15 (64 k each)
    const int tid = threadIdx.x;
    const int nt = tid & 15;        // n0 = nt*8
    const int bt = tid >> 4;        // b0 = bt*8
    __shared__ float xs[64][128];
    __shared__ float ws[128][64];
    const int kb = ks * 64;
    const bool isX = kb < E;
    const float* __restrict__ src = isX ? (xT + (size_t)kb * B) : (hT + (size_t)(kb - E) * B);
    // stage activations [k][b]
#pragma unroll
    for (int i = 0; i < 8; ++i) {
        int flat = i * 256 + tid;
        int kk = flat >> 5, b4 = flat & 31;
        *reinterpret_cast<float4*>(&xs[kk][b4 * 4]) =
            *reinterpret_cast<const float4*>(src + kk * B + b4 * 4);
    }
    // stage weights [n][k] swizzled: logical slot c stored at c ^ (n>>3)
    {
        int r = tid >> 1, kh = tid & 1;
        int nglob = ntile * 128 + r;
        int jrow = nglob >> 2, g = nglob & 3;
        const float* __restrict__ Wp = isX ? (W_ih + (size_t)(g * H + jrow) * E + kb)
                                           : (W_hh + (size_t)(g * H + jrow) * H + (kb - E));
#pragma unroll
        for (int c = 0; c < 8; ++c) {
            int slot = (kh * 8 + c) ^ (r >> 3);
            *reinterpret_cast<float4*>(&ws[r][slot * 4]) =
                *reinterpret_cast<const float4*>(Wp + kh * 32 + c * 4);
        }
    }
    __syncthreads();
    float acc[8][8];
#pragma unroll
    for (int i = 0; i < 8; ++i)
#pragma unroll
        for (int j = 0; j < 8; ++j) acc[i][j] = 0.0f;

    for (int k4 = 0; k4 < 16; ++k4) {
        float wr[8][4];
#pragma unroll
        for (int ni = 0; ni < 8; ++ni) {
            int slot = k4 ^ nt;       // n>>3 == nt for n = nt*8+ni, ni<8
            *reinterpret_cast<float4*>(wr[ni]) =
                *reinterpret_cast<const float4*>(&ws[nt * 8 + ni][slot * 4]);
        }
#pragma unroll
        for (int kk = 0; kk < 4; ++kk) {
            int k = k4 * 4 + kk;
            float4 x0 = *reinterpret_cast<const float4*>(&xs[k][bt * 8]);
            float4 x1 = *reinterpret_cast<const float4*>(&xs[k][bt * 8 + 4]);
            float xr[8] = {x0.x, x0.y, x0.z, x0.w, x1.x, x1.y, x1.z, x1.w};
#pragma unroll
            for (int bi = 0; bi < 8; ++bi)
#pragma unroll
                for (int ni = 0; ni < 8; ++ni) acc[bi][ni] += xr[bi] * wr[ni][kk];
        }
    }
#pragma unroll
    for (int ni = 0; ni < 8; ++ni) {
        size_t n = (size_t)ks * NG + ntile * 128 + nt * 8 + ni;
#pragma unroll
        for (int b4 = 0; b4 < 2; ++b4) {
            float4 col = make_float4(acc[b4 * 4 + 0][ni], acc[b4 * 4 + 1][ni],
                                     acc[b4 * 4 + 2][ni], acc[b4 * 4 + 3][ni]);
            *reinterpret_cast<float4*>(&pT[n * B + bt * 8 + b4 * 4]) = col;
        }
    }
}

// ---- LSTM cell: sum 16 k-split partials + bias, update cT/hT, emit h hi/lo --
__global__ __launch_bounds__(256) void cell_kernel(const float* __restrict__ pT,
                                                   const float* __restrict__ b_ih,
                                                   const float* __restrict__ b_hh,
                                                   float* __restrict__ cT,
                                                   float* __restrict__ hT,
                                                   short* __restrict__ h_hi,
                                                   short* __restrict__ h_lo) {
    int tid = threadIdx.x;
    int b = tid & 127;
    int j = blockIdx.x * 2 + (tid >> 7);
    float gs[4];
#pragma unroll
    for (int g = 0; g < 4; ++g) {
        float s = b_ih[g * H + j] + b_hh[g * H + j];
#pragma unroll
        for (int ks = 0; ks < KSPLIT; ++ks) s += pT[((size_t)ks * NG + 4 * j + g) * B + b];
        gs[g] = s;
    }
    float ig = sigmoidf_(gs[0]);
    float fg = sigmoidf_(gs[1]);
    float gg = tanhf(gs[2]);
    float og = sigmoidf_(gs[3]);
    float c = fg * cT[j * B + b] + ig * gg;
    cT[j * B + b] = c;
    float h = og * tanhf(c);
    hT[j * B + b] = h;
    short hs = f2bf_s(h);
    h_hi[b * 512 + j] = hs;
    h_lo[b * 512 + j] = f2bf_s(h - bfs2f(hs));
}

// ---- logits via MFMA (split bf16) + per-16n-tile top-2 keys -----------------
// Block: 512 thr / 8 waves; tile M=128(all b) x N=128; wave w owns 16 n.
// LDS: h chunk [128 b][64 k] bf16 hi/lo, 16B slots swizzled by b&7.
__global__ __launch_bounds__(512) void logits_mfma_kernel(const short* __restrict__ h_hi,
                                                          const short* __restrict__ h_lo,
                                                          const short* __restrict__ W_hi,
                                                          const short* __restrict__ W_lo,
                                                          const float* __restrict__ b_fc,
                                                          ull* __restrict__ pk1,
                                                          ull* __restrict__ pk2) {
    const int blk = blockIdx.x;          // 0..249
    const int n0 = blk * NTILE_L;
    const int tid = threadIdx.x;
    const int w = tid >> 6;              // wave 0..7
    const int l = tid & 63;
    const int l15 = l & 15, lg = l >> 4;
    __shared__ short lds_h[2][128 * 64];
    f32x4 acc[8];
#pragma unroll
    for (int mt = 0; mt < 8; ++mt) acc[mt] = (f32x4){0.f, 0.f, 0.f, 0.f};

    const int nr = n0 + w * 16 + l15;    // this lane's W row (n)
    for (int cc = 0; cc < 8; ++cc) {
        const int kb = cc * 64;
        __syncthreads();
        // stage h chunk (hi+lo): 1024 16B-slots each, 512 threads x 2
#pragma unroll
        for (int i = 0; i < 2; ++i) {
            int flat = tid + i * 512;
            int row = flat >> 3, c = flat & 7;
            int dst = row * 64 + ((c ^ (row & 7)) << 3);
            *reinterpret_cast<short8v*>(&lds_h[0][dst]) =
                *reinterpret_cast<const short8v*>(&h_hi[row * 512 + kb + c * 8]);
            *reinterpret_cast<short8v*>(&lds_h[1][dst]) =
                *reinterpret_cast<const short8v*>(&h_lo[row * 512 + kb + c * 8]);
        }
        __syncthreads();
        // B fragments for this wave's n, both k-sub-steps
        short8v bh[2], bl[2];
#pragma unroll
        for (int ks2 = 0; ks2 < 2; ++ks2) {
            size_t off = (size_t)nr * 512 + kb + ks2 * 32 + lg * 8;
            bh[ks2] = *reinterpret_cast<const short8v*>(&W_hi[off]);
            bl[ks2] = *reinterpret_cast<const short8v*>(&W_lo[off]);
        }
#pragma unroll
        for (int ks2 = 0; ks2 < 2; ++ks2) {
#pragma unroll
            for (int mt = 0; mt < 8; ++mt) {
                int row = mt * 16 + l15;
                int cslot = ks2 * 4 + lg;
                int off = row * 64 + ((cslot ^ (row & 7)) << 3);
                short8v ah = *reinterpret_cast<const short8v*>(&lds_h[0][off]);
                short8v al = *reinterpret_cast<const short8v*>(&lds_h[1][off]);
                acc[mt] = __builtin_amdgcn_mfma_f32_16x16x32_bf16(ah, bh[ks2], acc[mt], 0, 0, 0);
                acc[mt] = __builtin_amdgcn_mfma_f32_16x16x32_bf16(ah, bl[ks2], acc[mt], 0, 0, 0);
                acc[mt] = __builtin_amdgcn_mfma_f32_16x16x32_bf16(al, bh[ks2], acc[mt], 0, 0, 0);
            }
        }
    }
    // epilogue: bias + per-b-row top-2 over this wave's 16 n (lanes l15)
    const float bias = b_fc[nr];
    const unsigned int nglob = (unsigned int)nr;
    const int wt = blk * 8 + w;
#pragma unroll
    for (int mt = 0; mt < 8; ++mt) {
#pragma unroll
        for (int r = 0; r < 4; ++r) {
            float v = acc[mt][r] + bias;
            ull k1 = makekey(v, nglob), k2 = 0;
#pragma unroll
            for (int off = 1; off < 16; off <<= 1) {
                ull o1 = shflx_u64(k1, off);
                ull o2 = shflx_u64(k2, off);
                merge2(k1, k2, o1, o2);
            }
            if (l15 == 0) {
                int brow = mt * 16 + lg * 4 + r;
                pk1[(size_t)brow * WTPAD + wt] = k1;
                pk2[(size_t)brow * WTPAD + wt] = k2;
            }
        }
    }
}

// ---- final: global top-2 keys -> exact fp32 recompute -> outputs + gather ---
__global__ __launch_bounds__(256) void argmax2_kernel(const ull* __restrict__ pk1,
                                                      const ull* __restrict__ pk2,
                                                      const float* __restrict__ hT,
                                                      const float* __restrict__ W_fc,
                                                      const float* __restrict__ b_fc,
                                                      const float* __restrict__ emb,
                                                      float* __restrict__ xT,
                                                      float* __restrict__ out,
                                                      int t) {
    const int b = blockIdx.x;
    const int tid = threadIdx.x;
    ull k1 = 0, k2 = 0;
#pragma unroll
    for (int i = 0; i < 8; ++i) {
        int wt = tid + i * 256;
        if (wt < WTILES)
            merge2(k1, k2, pk1[(size_t)b * WTPAD + wt], pk2[(size_t)b * WTPAD + wt]);
    }
#pragma unroll
    for (int off = 1; off < 64; off <<= 1)
        merge2(k1, k2, shflx_u64(k1, off), shflx_u64(k2, off));
    __shared__ ull sk1[4], sk2[4];
    __shared__ int s_i1, s_i2;
    if ((tid & 63) == 0) { sk1[tid >> 6] = k1; sk2[tid >> 6] = k2; }
    __syncthreads();
    if (tid == 0) {
        k1 = sk1[0]; k2 = sk2[0];
#pragma unroll
        for (int wv = 1; wv < 4; ++wv) merge2(k1, k2, sk1[wv], sk2[wv]);
        s_i1 = keyidx(k1);
        s_i2 = keyidx(k2);
    }
    __syncthreads();
    const int i1 = s_i1, i2 = s_i2;
    // exact fp32 dots for both candidates (waves 0,1 -> i1; waves 2,3 -> i2)
    const int wv = tid >> 6, l = tid & 63;
    const int idx = (wv >> 1) ? i2 : i1;
    const int k0 = (wv & 1) * 256 + l * 4;
    float s = 0.0f;
#pragma unroll
    for (int kk = 0; kk < 4; ++kk)
        s += hT[(size_t)(k0 + kk) * B + b] * W_fc[(size_t)idx * E + k0 + kk];
#pragma unroll
    for (int off = 1; off < 64; off <<= 1) s += __shfl_xor(s, off);
    __shared__ float part[4];
    __shared__ int s_w;
    if (l == 0) part[wv] = s;
    __syncthreads();
    if (tid == 0) {
        float v0 = part[0] + part[1] + b_fc[i1];
        float v1 = part[2] + part[3] + b_fc[i2];
        int wi; float wvv;
        if (v1 > v0 || (v1 == v0 && i2 < i1)) { wi = i2; wvv = v1; }
        else { wi = i1; wvv = v0; }
        out[b * TSEQ + t] = (float)wi;
        out[B * TSEQ + b * TSEQ + t] = wvv;
        s_w = wi;
    }
    __syncthreads();
    const int widx = s_w;
    xT[(size_t)tid * B + b] = emb[(size_t)widx * E + tid];
    xT[(size_t)(tid + 256) * B + b] = emb[(size_t)widx * E + tid + 256];
}

// ======================= fallback (R1 fp32 path) ============================
#define NBLK_OLD 500
#define PSTRIDE 512

__global__ __launch_bounds__(256) void gates_old(const float* __restrict__ xT,
                                                 const float* __restrict__ hT,
                                                 const float* __restrict__ W_ih,
                                                 const float* __restrict__ W_hh,
                                                 float* __restrict__ pT) {
    const int ntile = blockIdx.x;
    const int ks = blockIdx.y;
    const int tid = threadIdx.x;
    const int nt = tid & 7;
    const int bt = tid >> 3;
    __shared__ float xs[64][132];
    __shared__ float ws[64][36];
    float acc[4][4];
#pragma unroll
    for (int i = 0; i < 4; ++i)
#pragma unroll
        for (int j = 0; j < 4; ++j) acc[i][j] = 0.0f;
    for (int ch = 0; ch < 4; ++ch) {
        const int kb = ks * 256 + ch * 64;
        const bool isX = (kb < E);
        const float* __restrict__ src = isX ? (xT + (size_t)kb * B) : (hT + (size_t)(kb - E) * B);
#pragma unroll
        for (int i = 0; i < 8; ++i) {
            int kk = tid >> 2;
            int bb = (tid & 3) * 32 + i * 4;
            *reinterpret_cast<float4*>(&xs[kk][bb]) =
                *reinterpret_cast<const float4*>(src + kk * B + bb);
        }
#pragma unroll
        for (int i = 0; i < 2; ++i) {
            int flat = tid * 8 + i * 4;
            int r = flat >> 6;
            int kk = flat & 63;
            int nglob = ntile * 32 + r;
            int jrow = nglob >> 2, gg = nglob & 3;
            const float* __restrict__ Wp = isX ? (W_ih + (size_t)(gg * H + jrow) * E + kb)
                                               : (W_hh + (size_t)(gg * H + jrow) * H + (kb - E));
            float4 wv = *reinterpret_cast<const float4*>(Wp + kk);
            ws[kk + 0][r] = wv.x; ws[kk + 1][r] = wv.y;
            ws[kk + 2][r] = wv.z; ws[kk + 3][r] = wv.w;
        }
        __syncthreads();
#pragma unroll
        for (int k = 0; k < 64; ++k) {
            const float4 xv = *reinterpret_cast<const float4*>(&xs[k][bt * 4]);
            const float4 wv = *reinterpret_cast<const float4*>(&ws[k][nt * 4]);
            float xr[4] = {xv.x, xv.y, xv.z, xv.w};
            float wr[4] = {wv.x, wv.y, wv.z, wv.w};
#pragma unroll
            for (int i = 0; i < 4; ++i)
#pragma unroll
                for (int j = 0; j < 4; ++j) acc[i][j] += xr[i] * wr[j];
        }
        __syncthreads();
    }
#pragma unroll
    for (int nj = 0; nj < 4; ++nj) {
        float4 col = make_float4(acc[0][nj], acc[1][nj], acc[2][nj], acc[3][nj]);
        size_t n = (size_t)ks * NG + ntile * 32 + nt * 4 + nj;
        *reinterpret_cast<float4*>(&pT[n * B + bt * 4]) = col;
    }
}

__global__ __launch_bounds__(256) void cell_old(const float* __restrict__ pT,
                                                const float* __restrict__ b_ih,
                                                const float* __restrict__ b_hh,
                                                float* __restrict__ cT,
                                                float* __restrict__ hT) {
    int tid = threadIdx.x;
    int b = tid & 127;
    int j = blockIdx.x * 2 + (tid >> 7);
    float gs[4];
#pragma unroll
    for (int g = 0; g < 4; ++g) {
        float s = b_ih[g * H + j] + b_hh[g * H + j];
#pragma unroll
        for (int ks = 0; ks < 4; ++ks) s += pT[((size_t)ks * NG + 4 * j + g) * B + b];
        gs[g] = s;
    }
    float ig = sigmoidf_(gs[0]);
    float fg = sigmoidf_(gs[1]);
    float gg = tanhf(gs[2]);
    float og = sigmoidf_(gs[3]);
    float c = fg * cT[j * B + b] + ig * gg;
    cT[j * B + b] = c;
    hT[j * B + b] = og * tanhf(c);
}

__global__ __launch_bounds__(256) void logits_old(const float* __restrict__ hT,
                                                  const float* __restrict__ W_fc,
                                                  const float* __restrict__ b_fc,
                                                  float* __restrict__ pval,
                                                  int* __restrict__ pidx) {
    const int nblk = blockIdx.x;
    const int tid = threadIdx.x;
    const int nt = tid & 7;
    const int bt = tid >> 3;
    __shared__ float hs[64][132];
    __shared__ float wsl[64][68];
    float acc[4][8];
#pragma unroll
    for (int i = 0; i < 4; ++i)
#pragma unroll
        for (int j = 0; j < 8; ++j) acc[i][j] = 0.0f;
    for (int ch = 0; ch < 8; ++ch) {
        const int kb = ch * 64;
#pragma unroll
        for (int i = 0; i < 8; ++i) {
            int kk = tid >> 2;
            int bb = (tid & 3) * 32 + i * 4;
            *reinterpret_cast<float4*>(&hs[kk][bb]) =
                *reinterpret_cast<const float4*>(hT + (size_t)(kb + kk) * B + bb);
        }
#pragma unroll
        for (int i = 0; i < 4; ++i) {
            int r = tid >> 2;
            int kk = (tid & 3) * 16 + i * 4;
            float4 wv = *reinterpret_cast<const float4*>(W_fc + (size_t)(nblk * 64 + r) * E + kb + kk);
            wsl[kk + 0][r] = wv.x; wsl[kk + 1][r] = wv.y;
            wsl[kk + 2][r] = wv.z; wsl[kk + 3][r] = wv.w;
        }
        __syncthreads();
#pragma unroll
        for (int k = 0; k < 64; ++k) {
            const float4 xv = *reinterpret_cast<const float4*>(&hs[k][bt * 4]);
            const float4 w0 = *reinterpret_cast<const float4*>(&wsl[k][nt * 4]);
            const float4 w1 = *reinterpret_cast<const float4*>(&wsl[k][nt * 4 + 32]);
            float xr[4] = {xv.x, xv.y, xv.z, xv.w};
            float wr[8] = {w0.x, w0.y, w0.z, w0.w, w1.x, w1.y, w1.z, w1.w};
#pragma unroll
            for (int i = 0; i < 4; ++i)
#pragma unroll
                for (int j = 0; j < 8; ++j) acc[i][j] += xr[i] * wr[j];
        }
        __syncthreads();
    }
    const int n_base = nblk * 64;
    float bf[8];
#pragma unroll
    for (int q = 0; q < 2; ++q)
#pragma unroll
        for (int c = 0; c < 4; ++c) bf[q * 4 + c] = b_fc[n_base + nt * 4 + c + 32 * q];
#pragma unroll
    for (int bi = 0; bi < 4; ++bi) {
        float bestv = -INFINITY;
        int bestn = 0x7fffffff;
#pragma unroll
        for (int q = 0; q < 2; ++q)
#pragma unroll
            for (int c = 0; c < 4; ++c) {
                float v = acc[bi][q * 4 + c] + bf[q * 4 + c];
                int n = n_base + nt * 4 + c + 32 * q;
                if (v > bestv || (v == bestv && n < bestn)) { bestv = v; bestn = n; }
            }
#pragma unroll
        for (int off = 1; off < 8; off <<= 1) {
            float ov = __shfl_xor(bestv, off);
            int on = __shfl_xor(bestn, off);
            if (ov > bestv || (ov == bestv && on < bestn)) { bestv = ov; bestn = on; }
        }
        if (nt == 0) {
            int b = bt * 4 + bi;
            pval[(size_t)b * PSTRIDE + nblk] = bestv;
            pidx[(size_t)b * PSTRIDE + nblk] = bestn;
        }
    }
}

__global__ __launch_bounds__(256) void argmax_old(const float* __restrict__ pval,
                                                  const int* __restrict__ pidx,
                                                  const float* __restrict__ emb,
                                                  float* __restrict__ xT,
                                                  float* __restrict__ out,
                                                  int t) {
    const int b = blockIdx.x;
    const int tid = threadIdx.x;
    float bestv = pval[(size_t)b * PSTRIDE + tid];
    int besti = pidx[(size_t)b * PSTRIDE + tid];
    if (tid < NBLK_OLD - 256) {
        float v = pval[(size_t)b * PSTRIDE + tid + 256];
        int ii = pidx[(size_t)b * PSTRIDE + tid + 256];
        if (v > bestv || (v == bestv && ii < besti)) { bestv = v; besti = ii; }
    }
#pragma unroll
    for (int off = 1; off < 64; off <<= 1) {
        float ov = __shfl_xor(bestv, off);
        int oi = __shfl_xor(besti, off);
        if (ov > bestv || (ov == bestv && oi < besti)) { bestv = ov; besti = oi; }
    }
    __shared__ float sv[4];
    __shared__ int si[4];
    __shared__ int sbest;
    if ((tid & 63) == 0) { sv[tid >> 6] = bestv; si[tid >> 6] = besti; }
    __syncthreads();
    if (tid == 0) {
        bestv = sv[0]; besti = si[0];
#pragma unroll
        for (int w = 1; w < 4; ++w)
            if (sv[w] > bestv || (sv[w] == bestv && si[w] < besti)) { bestv = sv[w]; besti = si[w]; }
        sbest = besti;
        out[b * TSEQ + t] = (float)besti;
        out[B * TSEQ + b * TSEQ + t] = bestv;
    }
    __syncthreads();
    const int idx = sbest;
    xT[(size_t)tid * B + b] = emb[(size_t)idx * E + tid];
    xT[(size_t)(tid + 256) * B + b] = emb[(size_t)idx * E + tid + 256];
}

// ============================================================================
extern "C" void kernel_launch(void* const* d_in, const int* in_sizes, int n_in,
                              void* d_out, int out_size, void* d_ws, size_t ws_size,
                              hipStream_t stream) {
    const float* features = (const float*)d_in[0];
    // d_in[1] = lengths: unused (fixed-length scan)
    const float* emb  = (const float*)d_in[2];
    const float* W_ih = (const float*)d_in[3];
    const float* W_hh = (const float*)d_in[4];
    const float* b_ih = (const float*)d_in[5];
    const float* b_hh = (const float*)d_in[6];
    const float* W_fc = (const float*)d_in[7];
    const float* b_fc = (const float*)d_in[8];
    float* out = (float*)d_out;

    constexpr size_t NB_W = (size_t)V * E * 2;            // 32,768,000 per half
    constexpr size_t NB_PK = (size_t)B * WTPAD * 8;       // 2,097,152
    constexpr size_t NB_ACT = (size_t)E * B * 4;          // 262,144
    constexpr size_t NB_PT = (size_t)KSPLIT * NG * B * 4; // 16,777,216
    constexpr size_t NB_HBF = (size_t)E * B * 2;          // 131,072
    constexpr size_t NEED = 2 * NB_W + 2 * NB_PK + 3 * NB_ACT + NB_PT + 2 * NB_HBF;

    if (ws_size >= NEED) {
        char* p = (char*)d_ws;
        short* W_hi = (short*)p;            p += NB_W;
        short* W_lo = (short*)p;            p += NB_W;
        ull* pk1 = (ull*)p;                 p += NB_PK;
        ull* pk2 = (ull*)p;                 p += NB_PK;
        float* xT = (float*)p;              p += NB_ACT;
        float* hT = (float*)p;              p += NB_ACT;
        float* cT = (float*)p;              p += NB_ACT;
        float* pT = (float*)p;              p += NB_PT;
        short* h_hi = (short*)p;            p += NB_HBF;
        short* h_lo = (short*)p;

        wsplit_kernel<<<8000, 256, 0, stream>>>(W_fc, W_hi, W_lo);
        init_kernel<<<256, 256, 0, stream>>>(features, xT, hT, cT);
        for (int t = 0; t < TSEQ; ++t) {
            gates_kernel<<<dim3(16, 16), 256, 0, stream>>>(xT, hT, W_ih, W_hh, pT);
            cell_kernel<<<256, 256, 0, stream>>>(pT, b_ih, b_hh, cT, hT, h_hi, h_lo);
            logits_mfma_kernel<<<NBLK_L, 512, 0, stream>>>(h_hi, h_lo, W_hi, W_lo, b_fc, pk1, pk2);
            argmax2_kernel<<<B, 256, 0, stream>>>(pk1, pk2, hT, W_fc, b_fc, emb, xT, out, t);
        }
    } else {
        float* ws = (float*)d_ws;
        float* xT = ws;
        float* hT = xT + 65536;
        float* cT = hT + 65536;
        float* pT = cT + 65536;              // 4*2048*128
        float* pval = pT + 1048576;
        int* pidx = (int*)(pval + (size_t)B * PSTRIDE);

        init_kernel<<<256, 256, 0, stream>>>(features, xT, hT, cT);
        for (int t = 0; t < TSEQ; ++t) {
            gates_old<<<dim3(64, 4), 256, 0, stream>>>(xT, hT, W_ih, W_hh, pT);
            cell_old<<<256, 256, 0, stream>>>(pT, b_ih, b_hh, cT, hT);
            logits_old<<<NBLK_OLD, 256, 0, stream>>>(hT, W_fc, b_fc, pval, pidx);
            argmax_old<<<B, 256, 0, stream>>>(pval, pidx, emb, xT, out, t);
        }
    }
}